// Round 3
// baseline (235.816 us; speedup 1.0000x reference)
//
#include <hip/hip_runtime.h>
#include <stdint.h>

#define NBINS 32
#define NBATCH 64
#define NPB (512 * 512)            // pixels per batch
#define BPB 32                     // blocks per batch
#define TPB 256
#define EPB (NPB / BPB)            // 8192 elems per block
#define ITERS (EPB / (TPB * 4))    // 8 float4 iterations per thread
#define COPIES 32                  // histogram privatization copies

// ws layout (uint32 words):
//   [0, 2048)      obs counts   [b*32 + j]
//   [2048, 4096)   pred counts  [b*32 + j]
//   [4096, 4160)   n_masked per batch
//   [4160]         mask-format flag: 1 => bytes (bool/u8), 0 => int32
#define WS_PRED 2048
#define WS_NM   4096
#define WS_FLAG 4160
#define WS_WORDS 4161

__global__ void detect_mask_kernel(const uint32_t* __restrict__ mw,
                                   uint32_t* __restrict__ flag) {
  uint32_t v = mw[blockIdx.x * blockDim.x + threadIdx.x];
  if (v > 1u) atomicOr(flag, 1u);
}

// Exact searchsorted(side='right')-1 with branchless +/-1 correction of the
// analytic guess. Valid whenever the analytic guess is within +/-1 of truth
// (guaranteed for f32 linspace-style edges).
__device__ __forceinline__ void bin_one(float x, bool m,
                                        const float* __restrict__ se,
                                        float e0, float eN, float invw,
                                        uint32_t* __restrict__ hbase) {
  if (!(m && x >= e0 && x <= eN)) return;   // NaN-safe validity
  int i = (int)((x - e0) * invw);           // >= 0 since x >= e0
  i = (i > NBINS - 1) ? NBINS - 1 : i;
  const float lo = se[i];                   // same-bin lanes: LDS broadcast
  const float hi = se[i + 1];
  i += (x >= hi) ? 1 : 0;
  i -= (x < lo) ? 1 : 0;
  i = (i < 0) ? 0 : ((i > NBINS - 1) ? NBINS - 1 : i);
  atomicAdd(hbase + i * COPIES, 1u);        // bank == copy, <=2-way
}

__global__ __launch_bounds__(TPB) void hist_kernel(
    const float* __restrict__ obs, const float* __restrict__ pred,
    const void* __restrict__ mask, const float* __restrict__ edges,
    uint32_t* __restrict__ ws) {
  __shared__ uint32_t h[2][NBINS][COPIES];  // 8 KiB, bank = copy index
  __shared__ float se[NBINS + 1];

  const int tid = threadIdx.x;

  // zero histograms: 2048 words, 8 per thread
  {
    uint32_t* hf = &h[0][0][0];
#pragma unroll
    for (int k = 0; k < 8; ++k) hf[k * TPB + tid] = 0u;
  }
  if (tid < NBINS + 1) se[tid] = edges[tid];
  __syncthreads();

  const uint32_t is_u8 = ws[WS_FLAG];       // uniform
  const int b = blockIdx.x / BPB;
  const int chunk = blockIdx.x % BPB;
  const size_t base_f4 = (((size_t)b * NPB) + ((size_t)chunk * EPB)) >> 2;

  const float4* __restrict__ o4 = (const float4*)obs;
  const float4* __restrict__ p4 = (const float4*)pred;
  const uint32_t* __restrict__ mwp = (const uint32_t*)mask;
  const int4* __restrict__ mip = (const int4*)mask;

  const float e0 = se[0];
  const float eN = se[NBINS];
  const float invw = (float)NBINS / (eN - e0);

  const int c = tid & 31;
  uint32_t* __restrict__ hb_o = &h[0][0][c];
  uint32_t* __restrict__ hb_p = &h[1][0][c];

  uint32_t nm = 0;

  // software-pipelined: prefetch it+1 while processing it
  float4 xo, xp;
  uint32_t mw_c = 0;
  int4 mi_c = {0, 0, 0, 0};
  {
    const size_t i0 = base_f4 + tid;
    xo = o4[i0];
    xp = p4[i0];
    if (is_u8) mw_c = mwp[i0]; else mi_c = mip[i0];
  }

#pragma unroll
  for (int it = 0; it < ITERS; ++it) {
    float4 nxo = xo, nxp = xp;
    uint32_t nmw = mw_c;
    int4 nmi = mi_c;
    if (it + 1 < ITERS) {
      const size_t ni = base_f4 + (size_t)((it + 1) * TPB + tid);
      nxo = o4[ni];
      nxp = p4[ni];
      if (is_u8) nmw = mwp[ni]; else nmi = mip[ni];
    }

    bool m0, m1, m2, m3;
    if (is_u8) {
      m0 = (mw_c & 0x000000ffu) != 0u;
      m1 = (mw_c & 0x0000ff00u) != 0u;
      m2 = (mw_c & 0x00ff0000u) != 0u;
      m3 = (mw_c & 0xff000000u) != 0u;
    } else {
      m0 = mi_c.x != 0; m1 = mi_c.y != 0; m2 = mi_c.z != 0; m3 = mi_c.w != 0;
    }
    nm += (m0 ? 1u : 0u) + (m1 ? 1u : 0u) + (m2 ? 1u : 0u) + (m3 ? 1u : 0u);

    bin_one(xo.x, m0, se, e0, eN, invw, hb_o);
    bin_one(xo.y, m1, se, e0, eN, invw, hb_o);
    bin_one(xo.z, m2, se, e0, eN, invw, hb_o);
    bin_one(xo.w, m3, se, e0, eN, invw, hb_o);

    bin_one(xp.x, m0, se, e0, eN, invw, hb_p);
    bin_one(xp.y, m1, se, e0, eN, invw, hb_p);
    bin_one(xp.z, m2, se, e0, eN, invw, hb_p);
    bin_one(xp.w, m3, se, e0, eN, invw, hb_p);

    xo = nxo; xp = nxp; mw_c = nmw; mi_c = nmi;
  }

  // n_masked: wave shuffle reduce, one atomic per wave
#pragma unroll
  for (int off = 32; off >= 1; off >>= 1) nm += __shfl_down(nm, off);
  if ((tid & 63) == 0) atomicAdd(&ws[WS_NM + b], nm);

  __syncthreads();

  // reduce the 32 copies; threads 0..63 each own one (arr,bin) pair
  if (tid < 2 * NBINS) {
    const int arr = tid >> 5;
    const int bin = tid & 31;
    uint32_t s = 0;
#pragma unroll
    for (int k = 0; k < COPIES; ++k)
      s += h[arr][bin][(k + tid) & 31];     // staggered: conflict-free
    if (s) atomicAdd(&ws[(arr ? WS_PRED : 0) + b * NBINS + bin], s);
  }
}

__global__ __launch_bounds__(64) void finalize_kernel(
    const uint32_t* __restrict__ ws, const float* __restrict__ edges,
    float* __restrict__ out) {
  __shared__ float pobs[NBATCH][NBINS + 1];   // +1 pad
  __shared__ float ppred[NBATCH][NBINS + 1];
  __shared__ float w_sh[NBINS];
  __shared__ float bw_sh[NBINS];
  __shared__ float w_scale;

  const int t = threadIdx.x;  // one batch per thread, 64 threads = 1 wave

  const uint32_t* co = ws + t * NBINS;
  const uint32_t* cp = ws + WS_PRED + t * NBINS;
  const uint32_t nmask = ws[WS_NM + t];

  float sum_o = 0.0f, sum_p = 0.0f;
#pragma unroll
  for (int j = 0; j < NBINS; ++j) {
    float vo = (nmask == 0u) ? 1.0f : (float)co[j];
    float vp = (nmask == 0u) ? 1.0f : (float)cp[j];
    pobs[t][j] = vo;  sum_o += vo;
    ppred[t][j] = vp; sum_p += vp;
  }
  const float inv_to = 1.0f / fmaxf(sum_o, 1.0f);
  const float inv_tp = 1.0f / fmaxf(sum_p, 1.0f);
#pragma unroll
  for (int j = 0; j < NBINS; ++j) {
    pobs[t][j] *= inv_to;
    ppred[t][j] = 0.95f * (ppred[t][j] * inv_tp) + 0.05f / (float)NBINS;
  }
  __syncthreads();

  if (t < NBINS) {
    float s = 0.0f;
#pragma unroll
    for (int b = 0; b < NBATCH; ++b) s += pobs[b][t];
    const float avg = s / (float)NBATCH;
    w_sh[t] = 1.0f / (avg + 1e-3f);
    const int j2 = (t < NBINS - 1) ? t : (NBINS - 2);
    const float mA = 0.5f * (edges[j2] + edges[j2 + 1]);
    const float mB = 0.5f * (edges[j2 + 1] + edges[j2 + 2]);
    bw_sh[t] = mB - mA;
  }
  __syncthreads();
  if (t == 0) {
    float sw = 0.0f;
#pragma unroll
    for (int j = 0; j < NBINS; ++j) sw += w_sh[j];
    w_scale = (float)NBINS / sw;
  }
  __syncthreads();

  float ce = 0.0f, w2 = 0.0f, cdf_o = 0.0f, cdf_p = 0.0f;
#pragma unroll
  for (int j = 0; j < NBINS; ++j) {
    const float po = pobs[t][j];
    const float pp = ppred[t][j];
    ce += -po * logf(pp + 1e-8f) * (w_sh[j] * w_scale);
    cdf_o += po;
    cdf_p += pp;
    const float d = cdf_o - cdf_p;
    w2 += d * d * bw_sh[j];
  }

  float ce_r = ce, w2_r = w2;
#pragma unroll
  for (int off = 32; off >= 1; off >>= 1) {
    ce_r += __shfl_down(ce_r, off);
    w2_r += __shfl_down(w2_r, off);
  }
  if (t == 0) {
    const float ce_m = ce_r / (float)NBATCH;
    const float w2_m = w2_r / (float)NBATCH;
    out[0] = (ce_m + 0.1f * w2_m) / (float)NBINS;
    out[1] = ce_m;
    out[2] = w2_m;
  }

#pragma unroll
  for (int j = 0; j < NBINS; ++j) {
    out[3 + t * NBINS + j] = pobs[t][j];
    out[3 + NBATCH * NBINS + t * NBINS + j] = ppred[t][j];
  }
}

extern "C" void kernel_launch(void* const* d_in, const int* in_sizes, int n_in,
                              void* d_out, int out_size, void* d_ws,
                              size_t ws_size, hipStream_t stream) {
  const float* obs = (const float*)d_in[0];
  const float* pred = (const float*)d_in[1];
  const void* mask = d_in[2];
  const float* edges = (const float*)d_in[3];
  float* out = (float*)d_out;
  uint32_t* ws = (uint32_t*)d_ws;

  hipMemsetAsync(d_ws, 0, WS_WORDS * sizeof(uint32_t), stream);
  detect_mask_kernel<<<64, 256, 0, stream>>>((const uint32_t*)mask,
                                             ws + WS_FLAG);
  hist_kernel<<<NBATCH * BPB, TPB, 0, stream>>>(obs, pred, mask, edges, ws);
  finalize_kernel<<<1, 64, 0, stream>>>(ws, edges, out);
}